// Round 1
// baseline (979.259 us; speedup 1.0000x reference)
//
#include <hip/hip_runtime.h>

// Problem constants (N == E == 8192, D == 256)
#define NROWS 8192
#define NCOLS 8192
#define DDIM  256
#define D4    64          // 256 floats = 64 float4 per row
#define CAP   786432      // nnz capacity per matrix; E[nnz]=671k, sigma~815 -> +140 sigma safe
#define ROW_CAP 1024      // per-row nnz staging cap; E[row nnz]=82, sigma~9

__global__ __launch_bounds__(256) void zero_kernel(int* __restrict__ p, int n) {
    int i = blockIdx.x * 256 + threadIdx.x;
    if (i < n) p[i] = 0;
}

// One block per row: scan the dense row (float4, coalesced), compact nonzeros
// into LDS, then append to the global CSR arrays with a single atomic per row.
__global__ __launch_bounds__(256) void extract_kernel(
        const float* __restrict__ M,
        int* __restrict__ row_start, int* __restrict__ row_cnt,
        int* __restrict__ csr_col, float* __restrict__ csr_val,
        int* __restrict__ nnz_counter) {
    __shared__ int s_cnt;
    __shared__ int s_base;
    __shared__ int   s_col[ROW_CAP];
    __shared__ float s_valv[ROW_CAP];
    const int r = blockIdx.x;
    const int tid = threadIdx.x;
    if (tid == 0) s_cnt = 0;
    __syncthreads();

    const float4* M4 = (const float4*)(M + (size_t)r * NCOLS);
    for (int c4 = tid; c4 < NCOLS / 4; c4 += 256) {
        float4 v = M4[c4];
        int c = c4 * 4;
        if (v.x != 0.f) { int p = atomicAdd(&s_cnt, 1); if (p < ROW_CAP) { s_col[p] = c + 0; s_valv[p] = v.x; } }
        if (v.y != 0.f) { int p = atomicAdd(&s_cnt, 1); if (p < ROW_CAP) { s_col[p] = c + 1; s_valv[p] = v.y; } }
        if (v.z != 0.f) { int p = atomicAdd(&s_cnt, 1); if (p < ROW_CAP) { s_col[p] = c + 2; s_valv[p] = v.z; } }
        if (v.w != 0.f) { int p = atomicAdd(&s_cnt, 1); if (p < ROW_CAP) { s_col[p] = c + 3; s_valv[p] = v.w; } }
    }
    __syncthreads();
    if (tid == 0) {
        int cnt = s_cnt; if (cnt > ROW_CAP) cnt = ROW_CAP;
        int base = atomicAdd(nnz_counter, cnt);
        int wr = CAP - base; if (wr < 0) wr = 0; if (wr > cnt) wr = cnt;
        row_start[r] = base;
        row_cnt[r]  = wr;
        s_base = base;
        s_cnt  = wr;
    }
    __syncthreads();
    const int base = s_base, cnt = s_cnt;
    for (int p = tid; p < cnt; p += 256) {
        csr_col[base + p] = s_col[p];
        csr_val[base + p] = s_valv[p];
    }
}

// Flat histogram over CSR entries -> per-column counts.
__global__ __launch_bounds__(256) void hist_kernel(
        const int* __restrict__ csr_col, const int* __restrict__ nnz_counter,
        int* __restrict__ col_cnt) {
    int p = blockIdx.x * 256 + threadIdx.x;
    int n = *nnz_counter; if (n > CAP) n = CAP;
    if (p < n) atomicAdd(&col_cnt[csr_col[p]], 1);
}

// Single-block exclusive prefix sum over 8192 bins -> col_start, and init cursor.
__global__ __launch_bounds__(256) void prefix_kernel(
        const int* __restrict__ cnt, int* __restrict__ start,
        int* __restrict__ cursor) {
    __shared__ int partial[256];
    const int tid = threadIdx.x;
    const int chunk = NCOLS / 256;   // 32
    const int base = tid * chunk;
    int sum = 0;
    for (int i = 0; i < chunk; ++i) sum += cnt[base + i];
    partial[tid] = sum;
    __syncthreads();
    if (tid == 0) {
        int acc = 0;
        for (int i = 0; i < 256; ++i) { int t = partial[i]; partial[i] = acc; acc += t; }
    }
    __syncthreads();
    int run = partial[tid];
    for (int i = 0; i < chunk; ++i) {
        int c = cnt[base + i];
        start[base + i]  = run;
        cursor[base + i] = run;
        run += c;
    }
}

// One block per CSR row: scatter entries into CSC slots via per-column cursors.
__global__ __launch_bounds__(256) void scatter_kernel(
        const int* __restrict__ row_start, const int* __restrict__ row_cnt,
        const int* __restrict__ csr_col, const float* __restrict__ csr_val,
        int* __restrict__ cursor,
        int* __restrict__ csc_row, float* __restrict__ csc_val) {
    const int r = blockIdx.x;
    const int s = row_start[r], c = row_cnt[r];
    for (int j = threadIdx.x; j < c; j += 256) {
        int col  = csr_col[s + j];
        float v  = csr_val[s + j];
        int slot = atomicAdd(&cursor[col], 1);
        csc_row[slot] = r;
        csc_val[slot] = v;
    }
}

// Y[r,:] = sum_j val[j] * X[idx[j],:]  (one wave per output row; float4/lane)
__global__ __launch_bounds__(256) void spmm_kernel(
        const int* __restrict__ start, const int* __restrict__ cnt,
        const int* __restrict__ idx, const float* __restrict__ val,
        const float* __restrict__ X, float* __restrict__ Y, int leaky) {
    const int wave = threadIdx.x >> 6;
    const int lane = threadIdx.x & 63;
    const int r = blockIdx.x * 4 + wave;
    const int s = start[r], c = cnt[r];
    const float4* X4 = (const float4*)X;
    float4 acc = make_float4(0.f, 0.f, 0.f, 0.f);
    for (int j = 0; j < c; ++j) {
        int k  = idx[s + j];
        float v = val[s + j];
        float4 x = X4[(size_t)k * D4 + lane];
        acc.x += v * x.x;
        acc.y += v * x.y;
        acc.z += v * x.z;
        acc.w += v * x.w;
    }
    if (leaky) {
        acc.x = acc.x > 0.f ? acc.x : 0.2f * acc.x;
        acc.y = acc.y > 0.f ? acc.y : 0.2f * acc.y;
        acc.z = acc.z > 0.f ? acc.z : 0.2f * acc.z;
        acc.w = acc.w > 0.f ? acc.w : 0.2f * acc.w;
    }
    ((float4*)Y)[(size_t)r * D4 + lane] = acc;
}

extern "C" void kernel_launch(void* const* d_in, const int* in_sizes, int n_in,
                              void* d_out, int out_size, void* d_ws, size_t ws_size,
                              hipStream_t stream) {
    const float* Bm   = (const float*)d_in[0];  // inp_adj [E, N]
    const float* Am   = (const float*)d_in[1];  // att_adj [N, E]
    const float* embs = (const float*)d_in[2];  // [N, D]
    float* out = (float*)d_out;

    // Carve workspace (256 B aligned slices). Total ~41 MB.
    char* w = (char*)d_ws;
    auto alloc = [&](size_t bytes) -> char* {
        char* p = w;
        w += (bytes + 255) & ~(size_t)255;
        return p;
    };
    float* t1 = (float*)alloc((size_t)NROWS * DDIM * 4);  // [E, D]
    float* t2 = (float*)alloc((size_t)NROWS * DDIM * 4);  // [N, D]
    float* t3 = t1;                                       // alias: t1 dead after pass 2

    // contiguous zero region: colcntA | colcntB | nnzA | nnzB
    int* colcntA = (int*)alloc(NCOLS * 4);
    int* colcntB = (int*)alloc(NCOLS * 4);
    int* nnzA = (int*)alloc(4);
    int* nnzB = (int*)alloc(4);

    int* rowA_start = (int*)alloc(NROWS * 4);
    int* rowA_cnt   = (int*)alloc(NROWS * 4);
    int* rowB_start = (int*)alloc(NROWS * 4);
    int* rowB_cnt   = (int*)alloc(NROWS * 4);
    int* colA_start = (int*)alloc(NCOLS * 4);
    int* colA_cur   = (int*)alloc(NCOLS * 4);
    int* colB_start = (int*)alloc(NCOLS * 4);
    int* colB_cur   = (int*)alloc(NCOLS * 4);

    int*   csrA_col = (int*)alloc((size_t)CAP * 4);
    float* csrA_val = (float*)alloc((size_t)CAP * 4);
    int*   cscA_row = (int*)alloc((size_t)CAP * 4);
    float* cscA_val = (float*)alloc((size_t)CAP * 4);
    int*   csrB_col = (int*)alloc((size_t)CAP * 4);
    float* csrB_val = (float*)alloc((size_t)CAP * 4);
    int*   cscB_row = (int*)alloc((size_t)CAP * 4);
    float* cscB_val = (float*)alloc((size_t)CAP * 4);

    // 1) zero counters (colcntA, colcntB, nnzA, nnzB are contiguous ints)
    {
        int nz = 2 * NCOLS + 2 + 126;  // cover alignment padding between slices
        zero_kernel<<<(nz + 255) / 256, 256, 0, stream>>>(colcntA, nz);
    }
    // 2) extract CSR of A and B (the two 256 MB dense scans)
    extract_kernel<<<NROWS, 256, 0, stream>>>(Am, rowA_start, rowA_cnt, csrA_col, csrA_val, nnzA);
    extract_kernel<<<NROWS, 256, 0, stream>>>(Bm, rowB_start, rowB_cnt, csrB_col, csrB_val, nnzB);
    // 3) counting sort -> CSC
    hist_kernel<<<CAP / 256, 256, 0, stream>>>(csrA_col, nnzA, colcntA);
    hist_kernel<<<CAP / 256, 256, 0, stream>>>(csrB_col, nnzB, colcntB);
    prefix_kernel<<<1, 256, 0, stream>>>(colcntA, colA_start, colA_cur);
    prefix_kernel<<<1, 256, 0, stream>>>(colcntB, colB_start, colB_cur);
    scatter_kernel<<<NROWS, 256, 0, stream>>>(rowA_start, rowA_cnt, csrA_col, csrA_val,
                                              colA_cur, cscA_row, cscA_val);
    scatter_kernel<<<NROWS, 256, 0, stream>>>(rowB_start, rowB_cnt, csrB_col, csrB_val,
                                              colB_cur, cscB_row, cscB_val);
    // 4) four SpMM passes: out = A (B (B^T (A^T embs)))
    spmm_kernel<<<NROWS / 4, 256, 0, stream>>>(colA_start, colcntA, cscA_row, cscA_val, embs, t1, 0);
    spmm_kernel<<<NROWS / 4, 256, 0, stream>>>(colB_start, colcntB, cscB_row, cscB_val, t1, t2, 0);
    spmm_kernel<<<NROWS / 4, 256, 0, stream>>>(rowB_start, rowB_cnt, csrB_col, csrB_val, t2, t3, 0);
    spmm_kernel<<<NROWS / 4, 256, 0, stream>>>(rowA_start, rowA_cnt, csrA_col, csrA_val, t3, out, 1);

    (void)in_sizes; (void)n_in; (void)out_size; (void)ws_size;
}